// Round 3
// baseline (492.703 us; speedup 1.0000x reference)
//
#include <hip/hip_runtime.h>

// OctreeDWConvBn: out[n,c] = BN_c( sum_k data[neigh[n,k],c] * weight[k,c] )
// N=131072, C=192, K=27. fp32 in/out; gathered operand staged as bf16.
// R7 (resubmit; R2 was a broker timeout, kernel never ran):
// channel-split gather. conv runs as 3 sequential passes over 64-channel
// slabs, each gathering from a pass-major 16.8 MB array (vs 50.3 MB), so a
// much larger fraction of the random-gather working set is L2-resident per
// XCD and every row-gather is exactly one 128-B line (64 lanes x 2B).
//   1) cvt_zero   : fp32 -> bf16, restaged pass-major [3][N][64]; zero stats
//   2) conv_pass  : x3, one 64-ch slab each; 256 thr = 4 waves x 16 nodes
//   3) bn_apply_fused : unchanged (reads [N][192] conv_bf)

static constexpr int NN  = 131072;   // nodes
static constexpr int CC  = 192;      // channels
static constexpr int KK  = 27;       // stencil taps
static constexpr int CP  = 64;       // channels per pass
static constexpr int NP  = 3;        // passes
static constexpr int NBP = 16;       // nodes per wave-group (serial)
static constexpr float BN_EPS = 1e-5f;

typedef float          f32x4 __attribute__((ext_vector_type(4)));
typedef unsigned short u16x4 __attribute__((ext_vector_type(4)));
typedef unsigned int   u32x2 __attribute__((ext_vector_type(2)));

__device__ __forceinline__ unsigned short f2bf_rne(float x) {
    unsigned u = __float_as_uint(x);
    return (unsigned short)((u + 0x7FFFu + ((u >> 16) & 1u)) >> 16);
}
__device__ __forceinline__ float bf2f(unsigned short b) {
    return __uint_as_float((unsigned)b << 16);
}

// ---------------------------------------------------------------------------
// Kernel 1: fp32 -> bf16 staging of `data` into pass-major [NP][NN][CP],
// plus zeroing the stat buffers. fp32 source is dead after this -> NT loads.
// dst stays cached (it is the conv gather target).
// ---------------------------------------------------------------------------
__global__ __launch_bounds__(256) void cvt_zero(
    const float* __restrict__ src, unsigned short* __restrict__ dst,
    float* __restrict__ stats /* [2*CC] sum|sumsq */)
{
    if (blockIdx.x < 2 && threadIdx.x < CC)
        stats[blockIdx.x * CC + threadIdx.x] = 0.f;

    const int i   = blockIdx.x * 256 + threadIdx.x;   // float4 index
    const int lin = i * 4;                            // linear channel index
    const int n   = lin / CC;
    const int c   = lin - n * CC;
    const int p   = c >> 6;          // pass slab
    const int cr  = c & 63;          // channel within slab (4-aligned)

    const f32x4 v =
        __builtin_nontemporal_load(reinterpret_cast<const f32x4*>(src) + i);
    u16x4 o;
    o.x = f2bf_rne(v.x); o.y = f2bf_rne(v.y);
    o.z = f2bf_rne(v.z); o.w = f2bf_rne(v.w);
    *reinterpret_cast<u16x4*>(
        dst + (size_t)p * NN * CP + (size_t)n * CP + cr) = o;
}

// ---------------------------------------------------------------------------
// Kernel 2: one 64-channel conv pass + partial BN sums.
// Block = 256 threads = 4 waves; each wave owns an independent node stream
// (wave-uniform node -> readfirstlane -> s_load of neighbor indices).
// Gather: lane c loads ushort at dataP[node*64+c] -> one aligned 128-B line
// per row per wave. Weights for the slab live in LDS (2-way bank = free).
// Conv result NT-stored into the [NN][CC] conv_bf at the slab's offset.
// ---------------------------------------------------------------------------
__global__ __launch_bounds__(256, 8) void conv_pass(
    const unsigned short* __restrict__ dataP,     // [NN, CP] bf16 bits (slab)
    const int*   __restrict__ neigh,              // [NN, KK]
    const float* __restrict__ weight,             // [KK, CC]
    const int pass,
    unsigned short* __restrict__ conv_bf,         // [NN, CC] bf16 bits (ws)
    float*       __restrict__ ch_sum,             // [CC]
    float*       __restrict__ ch_sumsq)           // [CC]
{
    __shared__ float lds_w[KK * CP];              // 6912 B
    __shared__ float red[2][4][CP];               // 2048 B cross-wave reduce

    const int t = threadIdx.x;
    const int g = t >> 6;            // wave id 0..3 (independent node stream)
    const int c = t & 63;            // channel within slab

    for (int idx = t; idx < KK * CP; idx += 256)
        lds_w[idx] = weight[(idx >> 6) * CC + pass * CP + (idx & 63)];
    __syncthreads();

    const int base = (blockIdx.x * 4 + g) * NBP;

    float s = 0.f, ss = 0.f;

    for (int n = 0; n < NBP; ++n) {
        // node is wave-uniform; readfirstlane makes that provable -> s_load.
        const int node = __builtin_amdgcn_readfirstlane(base + n);
        const int* nrow = neigh + (size_t)node * KK;

        unsigned short r[KK];
#pragma unroll
        for (int k = 0; k < KK; ++k)
            r[k] = dataP[(size_t)nrow[k] * CP + c];

        float acc = 0.f;
#pragma unroll
        for (int k = 0; k < KK; ++k)
            acc = fmaf(bf2f(r[k]), lds_w[k * CP + c], acc);

        __builtin_nontemporal_store(
            f2bf_rne(acc), &conv_bf[(size_t)node * CC + pass * CP + c]);
        s  += acc;
        ss += acc * acc;
    }

    red[0][g][c] = s;
    red[1][g][c] = ss;
    __syncthreads();
    if (g == 0) {
        const float S  = red[0][0][c] + red[0][1][c] + red[0][2][c] + red[0][3][c];
        const float SS = red[1][0][c] + red[1][1][c] + red[1][2][c] + red[1][3][c];
        atomicAdd(&ch_sum[pass * CP + c],   S);
        atomicAdd(&ch_sumsq[pass * CP + c], SS);
    }
}

// ---------------------------------------------------------------------------
// Kernel 3: fused BN finalize + normalize (unchanged from R6).
// ---------------------------------------------------------------------------
__global__ __launch_bounds__(192) void bn_apply_fused(
    const unsigned int* __restrict__ conv_bf,   // [NN*96] u32 pairs
    const float* __restrict__ ch_sum,
    const float* __restrict__ ch_sumsq,
    const float* __restrict__ gamma,
    const float* __restrict__ beta,
    float* __restrict__ out)             // [NN, CC]
{
    const int t = threadIdx.x;
    const int g = t / 48;          // node subgroup 0..3
    const int q = t - g * 48;      // channel quad 0..47 (fixed per thread)
    const int cb = q * 4;

    const float inv_n = 1.0f / (float)NN;
    f32x4 sc, bi;
    {
        float m0 = ch_sum[cb + 0] * inv_n, m1 = ch_sum[cb + 1] * inv_n;
        float m2 = ch_sum[cb + 2] * inv_n, m3 = ch_sum[cb + 3] * inv_n;
        float v0 = ch_sumsq[cb + 0] * inv_n - m0 * m0;
        float v1 = ch_sumsq[cb + 1] * inv_n - m1 * m1;
        float v2 = ch_sumsq[cb + 2] * inv_n - m2 * m2;
        float v3 = ch_sumsq[cb + 3] * inv_n - m3 * m3;
        sc.x = gamma[cb + 0] * rsqrtf(v0 + BN_EPS);
        sc.y = gamma[cb + 1] * rsqrtf(v1 + BN_EPS);
        sc.z = gamma[cb + 2] * rsqrtf(v2 + BN_EPS);
        sc.w = gamma[cb + 3] * rsqrtf(v3 + BN_EPS);
        bi.x = beta[cb + 0] - m0 * sc.x;
        bi.y = beta[cb + 1] - m1 * sc.y;
        bi.z = beta[cb + 2] - m2 * sc.z;
        bi.w = beta[cb + 3] - m3 * sc.w;
    }

    for (int nb = blockIdx.x; nb < NN / 4; nb += gridDim.x) {
        const int node = nb * 4 + g;
        const int i = node * 48 + q;
        const u32x2 u = __builtin_nontemporal_load(
            reinterpret_cast<const u32x2*>(conv_bf) + i);
        f32x4 v;
        v.x = fmaf(__uint_as_float(u.x << 16),         sc.x, bi.x);
        v.y = fmaf(__uint_as_float(u.x & 0xFFFF0000u), sc.y, bi.y);
        v.z = fmaf(__uint_as_float(u.y << 16),         sc.z, bi.z);
        v.w = fmaf(__uint_as_float(u.y & 0xFFFF0000u), sc.w, bi.w);
        __builtin_nontemporal_store(v, reinterpret_cast<f32x4*>(out) + i);
    }
}

// ---------------------------------------------------------------------------
// Fallback tier (ws too small): fp32 conv + fused apply on fp32.
// ---------------------------------------------------------------------------
__global__ __launch_bounds__(CC) void conv_bn_partial_f32(
    const float* __restrict__ data,
    const int*   __restrict__ neigh,
    const float* __restrict__ weight,
    float*       __restrict__ conv_out,
    float*       __restrict__ ch_sum,
    float*       __restrict__ ch_sumsq)
{
    const int c = threadIdx.x;
    const int base = blockIdx.x * 32;
    float w[KK];
#pragma unroll
    for (int k = 0; k < KK; ++k) w[k] = weight[k * CC + c];
    float s = 0.f, ss = 0.f;
    for (int n = 0; n < 32; ++n) {
        const int node = base + n;
        const int* nrow = neigh + node * KK;
        float acc = 0.f;
#pragma unroll
        for (int k = 0; k < KK; ++k)
            acc = fmaf(data[nrow[k] * CC + c], w[k], acc);
        conv_out[node * CC + c] = acc;
        s += acc; ss += acc * acc;
    }
    atomicAdd(&ch_sum[c], s);
    atomicAdd(&ch_sumsq[c], ss);
}

__global__ __launch_bounds__(192) void bn_apply_f32_fused(
    float* __restrict__ out,
    const float* __restrict__ ch_sum,
    const float* __restrict__ ch_sumsq,
    const float* __restrict__ gamma,
    const float* __restrict__ beta)
{
    const int t = threadIdx.x;
    const int g = t / 48;
    const int q = t - g * 48;
    const int cb = q * 4;
    const float inv_n = 1.0f / (float)NN;
    float4 sc, bi;
    float m0 = ch_sum[cb+0]*inv_n, m1 = ch_sum[cb+1]*inv_n;
    float m2 = ch_sum[cb+2]*inv_n, m3 = ch_sum[cb+3]*inv_n;
    sc.x = gamma[cb+0]*rsqrtf(ch_sumsq[cb+0]*inv_n - m0*m0 + BN_EPS);
    sc.y = gamma[cb+1]*rsqrtf(ch_sumsq[cb+1]*inv_n - m1*m1 + BN_EPS);
    sc.z = gamma[cb+2]*rsqrtf(ch_sumsq[cb+2]*inv_n - m2*m2 + BN_EPS);
    sc.w = gamma[cb+3]*rsqrtf(ch_sumsq[cb+3]*inv_n - m3*m3 + BN_EPS);
    bi.x = beta[cb+0] - m0*sc.x; bi.y = beta[cb+1] - m1*sc.y;
    bi.z = beta[cb+2] - m2*sc.z; bi.w = beta[cb+3] - m3*sc.w;
    for (int nb = blockIdx.x; nb < NN / 4; nb += gridDim.x) {
        const int i = (nb * 4 + g) * 48 + q;
        float4 v = reinterpret_cast<float4*>(out)[i];
        v.x = fmaf(v.x, sc.x, bi.x); v.y = fmaf(v.y, sc.y, bi.y);
        v.z = fmaf(v.z, sc.z, bi.z); v.w = fmaf(v.w, sc.w, bi.w);
        reinterpret_cast<float4*>(out)[i] = v;
    }
}

extern "C" void kernel_launch(void* const* d_in, const int* in_sizes, int n_in,
                              void* d_out, int out_size, void* d_ws, size_t ws_size,
                              hipStream_t stream) {
    const float* data   = (const float*)d_in[0];
    const int*   neigh  = (const int*)  d_in[1];
    const float* weight = (const float*)d_in[2];
    const float* gamma  = (const float*)d_in[3];
    const float* beta   = (const float*)d_in[4];
    float* out = (float*)d_out;

    // ws: stats 2*CC floats (padded to 4096 B) | data_bf 50.3 MB | conv_bf 50.3 MB
    float* stats    = (float*)d_ws;          // [0..191]=sum, [192..383]=sumsq
    float* ch_sum   = stats;
    float* ch_sumsq = stats + CC;
    unsigned short* data_bf = (unsigned short*)((char*)d_ws + 4096);
    const size_t stage_bytes = (size_t)NN * CC * sizeof(unsigned short);
    unsigned short* conv_bf =
        (unsigned short*)((char*)d_ws + 4096 + stage_bytes);

    const size_t need_full = 4096 + 2 * stage_bytes;
    const int vec_grid = (NN * CC / 4) / 256;   // 24576
    const int conv_grid = NN / (4 * NBP);       // 2048 (= one residency wave)

    if (ws_size >= need_full) {
        cvt_zero<<<vec_grid, 256, 0, stream>>>(data, data_bf, stats);
        for (int p = 0; p < NP; ++p)
            conv_pass<<<conv_grid, 256, 0, stream>>>(
                data_bf + (size_t)p * NN * CP, neigh, weight, p,
                conv_bf, ch_sum, ch_sumsq);
        bn_apply_fused<<<8192, 192, 0, stream>>>(
            (const unsigned int*)conv_bf, ch_sum, ch_sumsq, gamma, beta, out);
    } else {
        hipMemsetAsync(stats, 0, 2 * CC * sizeof(float), stream);
        conv_bn_partial_f32<<<NN / 32, CC, 0, stream>>>(
            data, neigh, weight, out, ch_sum, ch_sumsq);
        bn_apply_f32_fused<<<8192, 192, 0, stream>>>(
            out, ch_sum, ch_sumsq, gamma, beta);
    }
}

// Round 4
// 412.552 us; speedup vs baseline: 1.1943x; 1.1943x over previous
//
#include <hip/hip_runtime.h>

// OctreeDWConvBn: out[n,c] = BN_c( sum_k data[neigh[n,k],c] * weight[k,c] )
// N=131072, C=192, K=27. fp32 in/out; gathered operand staged as bf16.
// R8: revert R7's channel split (1-line gathers lost DRAM/L3 burst locality:
// 2.1 TB/s vs 2.9). Back to [N][192] layout, 192-thr blocks, 3 waves gather
// the 3 lines of each 384-B row simultaneously. Changes vs R6:
//   conv: weights in 27 VGPRs (not LDS) -> no LDS cap, no barrier;
//         __launch_bounds__(192,6) targets 24 waves/CU (was ~13).
//   cvt/bn: grid-stride with more per-thread work; bn reads uint4 (16B/lane)
//         and writes 2xfloat4 (32B/lane), block footprint stays contiguous.

static constexpr int NN = 131072;   // nodes
static constexpr int CC = 192;      // channels
static constexpr int KK = 27;       // stencil taps
static constexpr int NB = 32;       // nodes per block (serial)
static constexpr float BN_EPS = 1e-5f;

typedef float          f32x4 __attribute__((ext_vector_type(4)));
typedef unsigned short u16x4 __attribute__((ext_vector_type(4)));
typedef unsigned int   u32x4 __attribute__((ext_vector_type(4)));

__device__ __forceinline__ unsigned short f2bf_rne(float x) {
    unsigned u = __float_as_uint(x);
    return (unsigned short)((u + 0x7FFFu + ((u >> 16) & 1u)) >> 16);
}
__device__ __forceinline__ float bf2f(unsigned short b) {
    return __uint_as_float((unsigned)b << 16);
}

// ---------------------------------------------------------------------------
// Kernel 1: fp32 -> bf16 staging (same [N][CC] layout) + zero stat buffers.
// Grid-stride: 4096 blocks x 256 thr, 6 float4 iterations per thread.
// NT loads: fp32 source is dead after this kernel.
// ---------------------------------------------------------------------------
__global__ __launch_bounds__(256) void cvt_zero(
    const float* __restrict__ src, unsigned short* __restrict__ dst,
    float* __restrict__ stats /* [2*CC] sum|sumsq */)
{
    if (blockIdx.x < 2 && threadIdx.x < CC)
        stats[blockIdx.x * CC + threadIdx.x] = 0.f;

    const int tot    = NN * CC / 4;                 // float4 count
    const int stride = gridDim.x * 256;
    for (int i = blockIdx.x * 256 + threadIdx.x; i < tot; i += stride) {
        const f32x4 v = __builtin_nontemporal_load(
            reinterpret_cast<const f32x4*>(src) + i);
        u16x4 o;
        o.x = f2bf_rne(v.x); o.y = f2bf_rne(v.y);
        o.z = f2bf_rne(v.z); o.w = f2bf_rne(v.w);
        reinterpret_cast<u16x4*>(dst)[i] = o;
    }
}

// ---------------------------------------------------------------------------
// Kernel 2: depthwise conv + per-block partial BN sums (R4 gather shape).
// Block = 192 threads (thread = channel); the 3 waves gather the 3 x 128-B
// lines of each node row simultaneously -> 384-B burst per row. Weights in
// 27 VGPRs (channel is fixed per thread) -> zero LDS, zero barriers, so
// residency is wave-slot/VGPR-limited: (192,6) targets 24 waves/CU.
// ---------------------------------------------------------------------------
__global__ __launch_bounds__(192, 6) void conv_r8(
    const unsigned short* __restrict__ data_bf,   // [NN, CC] bf16 bits
    const int*   __restrict__ neigh,              // [NN, KK]
    const float* __restrict__ weight,             // [KK, CC]
    unsigned short* __restrict__ conv_bf,         // [NN, CC] bf16 bits (ws)
    float*       __restrict__ ch_sum,             // [CC]
    float*       __restrict__ ch_sumsq)           // [CC]
{
    const int c    = threadIdx.x;
    const int base = blockIdx.x * NB;

    float w[KK];
#pragma unroll
    for (int k = 0; k < KK; ++k) w[k] = weight[k * CC + c];

    float s = 0.f, ss = 0.f;

    for (int n = 0; n < NB; ++n) {
        const int node = base + n;                  // block-uniform
        const int* nrow = neigh + (size_t)node * KK; // uniform -> s_load

        unsigned short r[KK];
#pragma unroll
        for (int k = 0; k < KK; ++k)
            r[k] = data_bf[(size_t)nrow[k] * CC + c];

        float acc = 0.f;
#pragma unroll
        for (int k = 0; k < KK; ++k)
            acc = fmaf(bf2f(r[k]), w[k], acc);

        __builtin_nontemporal_store(f2bf_rne(acc),
                                    &conv_bf[(size_t)node * CC + c]);
        s  += acc;
        ss += acc * acc;
    }

    atomicAdd(&ch_sum[c],   s);
    atomicAdd(&ch_sumsq[c], ss);
}

// ---------------------------------------------------------------------------
// Kernel 3: fused BN finalize + normalize.
// Block = 192 threads: t = g*24 + q8 -> g = node subgroup 0..7, q8 = fixed
// channel OCTET 0..23 (8 channels). Per iteration: one uint4 load (8 bf16,
// 16 B/lane) + two float4 stores (32 B/lane). Block footprint per iteration
// stays exactly linear: i8 = nb*192 + t  (3 KiB read / 6 KiB write, contig).
// ---------------------------------------------------------------------------
__global__ __launch_bounds__(192) void bn_apply_fused(
    const u32x4* __restrict__ conv_u4,   // [NN*24] uint4 (8 bf16 each)
    const float* __restrict__ ch_sum,
    const float* __restrict__ ch_sumsq,
    const float* __restrict__ gamma,
    const float* __restrict__ beta,
    float* __restrict__ out)             // [NN, CC]
{
    const int t  = threadIdx.x;
    const int cb = (t % 24) * 8;         // first channel of this thread's octet

    const float inv_n = 1.0f / (float)NN;
    float sc[8], bi[8];
#pragma unroll
    for (int j = 0; j < 8; ++j) {
        const float m = ch_sum[cb + j] * inv_n;
        const float v = ch_sumsq[cb + j] * inv_n - m * m;
        sc[j] = gamma[cb + j] * rsqrtf(v + BN_EPS);
        bi[j] = beta[cb + j] - m * sc[j];
    }

    // Grid-stride over groups of 8 nodes; i8 = nb*192 + t is linear in t.
    f32x4* __restrict__ out4 = reinterpret_cast<f32x4*>(out);
    for (int nb = blockIdx.x; nb < NN / 8; nb += gridDim.x) {
        const int i8 = nb * 192 + t;
        const u32x4 u = __builtin_nontemporal_load(conv_u4 + i8);
        f32x4 a, b;
        a.x = fmaf(__uint_as_float(u.x << 16),         sc[0], bi[0]);
        a.y = fmaf(__uint_as_float(u.x & 0xFFFF0000u), sc[1], bi[1]);
        a.z = fmaf(__uint_as_float(u.y << 16),         sc[2], bi[2]);
        a.w = fmaf(__uint_as_float(u.y & 0xFFFF0000u), sc[3], bi[3]);
        b.x = fmaf(__uint_as_float(u.z << 16),         sc[4], bi[4]);
        b.y = fmaf(__uint_as_float(u.z & 0xFFFF0000u), sc[5], bi[5]);
        b.z = fmaf(__uint_as_float(u.w << 16),         sc[6], bi[6]);
        b.w = fmaf(__uint_as_float(u.w & 0xFFFF0000u), sc[7], bi[7]);
        __builtin_nontemporal_store(a, out4 + 2 * i8);
        __builtin_nontemporal_store(b, out4 + 2 * i8 + 1);
    }
}

// ---------------------------------------------------------------------------
// Fallback tier (ws too small): fp32 conv + fused apply on fp32.
// ---------------------------------------------------------------------------
__global__ __launch_bounds__(CC) void conv_bn_partial_f32(
    const float* __restrict__ data,
    const int*   __restrict__ neigh,
    const float* __restrict__ weight,
    float*       __restrict__ conv_out,
    float*       __restrict__ ch_sum,
    float*       __restrict__ ch_sumsq)
{
    const int c = threadIdx.x;
    const int base = blockIdx.x * NB;
    float w[KK];
#pragma unroll
    for (int k = 0; k < KK; ++k) w[k] = weight[k * CC + c];
    float s = 0.f, ss = 0.f;
    for (int n = 0; n < NB; ++n) {
        const int node = base + n;
        const int* nrow = neigh + node * KK;
        float acc = 0.f;
#pragma unroll
        for (int k = 0; k < KK; ++k)
            acc = fmaf(data[nrow[k] * CC + c], w[k], acc);
        conv_out[node * CC + c] = acc;
        s += acc; ss += acc * acc;
    }
    atomicAdd(&ch_sum[c], s);
    atomicAdd(&ch_sumsq[c], ss);
}

__global__ __launch_bounds__(192) void bn_apply_f32_fused(
    float* __restrict__ out,
    const float* __restrict__ ch_sum,
    const float* __restrict__ ch_sumsq,
    const float* __restrict__ gamma,
    const float* __restrict__ beta)
{
    const int t = threadIdx.x;
    const int g = t / 48;
    const int q = t - g * 48;
    const int cb = q * 4;
    const float inv_n = 1.0f / (float)NN;
    float4 sc, bi;
    float m0 = ch_sum[cb+0]*inv_n, m1 = ch_sum[cb+1]*inv_n;
    float m2 = ch_sum[cb+2]*inv_n, m3 = ch_sum[cb+3]*inv_n;
    sc.x = gamma[cb+0]*rsqrtf(ch_sumsq[cb+0]*inv_n - m0*m0 + BN_EPS);
    sc.y = gamma[cb+1]*rsqrtf(ch_sumsq[cb+1]*inv_n - m1*m1 + BN_EPS);
    sc.z = gamma[cb+2]*rsqrtf(ch_sumsq[cb+2]*inv_n - m2*m2 + BN_EPS);
    sc.w = gamma[cb+3]*rsqrtf(ch_sumsq[cb+3]*inv_n - m3*m3 + BN_EPS);
    bi.x = beta[cb+0] - m0*sc.x; bi.y = beta[cb+1] - m1*sc.y;
    bi.z = beta[cb+2] - m2*sc.z; bi.w = beta[cb+3] - m3*sc.w;
    for (int nb = blockIdx.x; nb < NN / 4; nb += gridDim.x) {
        const int i = (nb * 4 + g) * 48 + q;
        float4 v = reinterpret_cast<float4*>(out)[i];
        v.x = fmaf(v.x, sc.x, bi.x); v.y = fmaf(v.y, sc.y, bi.y);
        v.z = fmaf(v.z, sc.z, bi.z); v.w = fmaf(v.w, sc.w, bi.w);
        reinterpret_cast<float4*>(out)[i] = v;
    }
}

extern "C" void kernel_launch(void* const* d_in, const int* in_sizes, int n_in,
                              void* d_out, int out_size, void* d_ws, size_t ws_size,
                              hipStream_t stream) {
    const float* data   = (const float*)d_in[0];
    const int*   neigh  = (const int*)  d_in[1];
    const float* weight = (const float*)d_in[2];
    const float* gamma  = (const float*)d_in[3];
    const float* beta   = (const float*)d_in[4];
    float* out = (float*)d_out;

    // ws: stats 2*CC floats (padded to 4096 B) | data_bf 50.3 MB | conv_bf 50.3 MB
    float* stats    = (float*)d_ws;          // [0..191]=sum, [192..383]=sumsq
    float* ch_sum   = stats;
    float* ch_sumsq = stats + CC;
    unsigned short* data_bf = (unsigned short*)((char*)d_ws + 4096);
    const size_t stage_bytes = (size_t)NN * CC * sizeof(unsigned short);
    unsigned short* conv_bf =
        (unsigned short*)((char*)d_ws + 4096 + stage_bytes);

    const size_t need_full = 4096 + 2 * stage_bytes;

    if (ws_size >= need_full) {
        cvt_zero<<<4096, 256, 0, stream>>>(data, data_bf, stats);
        conv_r8<<<NN / NB, 192, 0, stream>>>(
            data_bf, neigh, weight, conv_bf, ch_sum, ch_sumsq);
        bn_apply_fused<<<4096, 192, 0, stream>>>(
            (const u32x4*)conv_bf, ch_sum, ch_sumsq, gamma, beta, out);
    } else {
        hipMemsetAsync(stats, 0, 2 * CC * sizeof(float), stream);
        conv_bn_partial_f32<<<NN / NB, CC, 0, stream>>>(
            data, neigh, weight, out, ch_sum, ch_sumsq);
        bn_apply_f32_fused<<<8192, 192, 0, stream>>>(
            out, ch_sum, ch_sumsq, gamma, beta);
    }
}